// Round 9
// baseline (457.173 us; speedup 1.0000x reference)
//
#include <hip/hip_runtime.h>

typedef __attribute__((ext_vector_type(8))) short bf16x8;
typedef __attribute__((ext_vector_type(4))) float f32x4;

#define HID 64
#define TSTEPS 256
#define BATCH 4096
#define BT 16
#define RST 1536          // bytes per LDS row
// per-row regions: X @0 (3 slots x 128B), H0 @384, H1 @768, H2 @1152 (3 x 128B each)

__device__ __forceinline__ float frcp(float x){ return __builtin_amdgcn_rcpf(x); }
__device__ __forceinline__ float fexp2(float x){ return __builtin_amdgcn_exp2f(x); }

__device__ __forceinline__ ushort f2bf(float f){
  unsigned u = __float_as_uint(f);
  u += 0x7fff + ((u>>16)&1);
  return (ushort)(u>>16);
}
__device__ __forceinline__ float bf2f(ushort u){ return __uint_as_float(((unsigned)u)<<16); }
__device__ __forceinline__ unsigned cvtpk(float lo, float hi){
  unsigned r;
  asm("v_cvt_pk_bf16_f32 %0, %1, %2" : "=v"(r) : "v"(lo), "v"(hi));
  return r;
}

__device__ __forceinline__ void poll4(volatile int* p, int tgt){
  for(;;){
    int m0 = p[0], m1 = p[1], m2 = p[2], m3 = p[3];
    if (min(min(m0,m1),min(m2,m3)) >= tgt) break;
    __builtin_amdgcn_s_sleep(1);
  }
}
__device__ __forceinline__ void poll8(volatile int* p, int tgt){
  for(;;){
    int m0 = p[0], m1 = p[1], m2 = p[2], m3 = p[3];
    int m4 = p[4], m5 = p[5], m6 = p[6], m7 = p[7];
    int m = min(min(min(m0,m1),min(m2,m3)), min(min(m4,m5),min(m6,m7)));
    if (m >= tgt) break;
    __builtin_amdgcn_s_sleep(1);
  }
}

// Weights pre-scaled by log2(e) (gates i,f,o) / 2*log2(e) (gate g).
__device__ __forceinline__ void load_wb_rt(const float* __restrict__ Wih,
    const float* __restrict__ Whh, const float* __restrict__ bih,
    const float* __restrict__ bhh, int IN, bf16x8 (&wf)[4][4], f32x4 (&bvv)[4],
    int s, int l15, int lhi){
  const float L2E = 1.4426950408889634f;
  const int nk = (IN + 64) >> 5;          // 3 (layer0) or 4
  #pragma unroll
  for (int g = 0; g < 4; ++g){
    const float sc = (g == 2) ? 2.f*L2E : L2E;
    int n = g*64 + s*16 + l15;            // A-frag row (m = lane&15)
    #pragma unroll
    for (int r = 0; r < 4; ++r){
      int nr = g*64 + s*16 + lhi*4 + r;   // C/D row (m = lhi*4+r)
      bvv[g][r] = (bih[nr] + bhh[nr]) * sc;
    }
    #pragma unroll
    for (int kt = 0; kt < 4; ++kt){
      if (kt < nk){
        int kb = kt*32 + lhi*8;           // same kappa(lane,j) as act-frag reads
        const float* src = (kb < IN) ? (Wih + (size_t)n*IN + kb)
                                     : (Whh + (size_t)n*64 + (kb - IN));
        bf16x8 v;
        #pragma unroll
        for (int j = 0; j < 8; ++j) v[j] = (short)f2bf(src[j] * sc);
        wf[kt][g] = v;
      }
    }
  }
}

// Merged-denominator LSTM cell: 5 exp2 + 2 rcp per cell (pre-scaled gates).
__device__ __forceinline__ void ew4(const f32x4 (&A)[4], float (&cst)[4],
                                    unsigned &p01, unsigned &p23){
  float h[4];
  #pragma unroll
  for (int r = 0; r < 4; ++r){
    float Ai = fexp2(-A[0][r]);
    float Bf = fexp2(-A[1][r]);
    float G  = fexp2( A[2][r]);
    float O  = fexp2(-A[3][r]);
    float a1 = 1.f + Ai, b1 = 1.f + Bf, gp = G + 1.f, gm = G - 1.f;
    float cp = (cst[r]*a1*gp + b1*gm) * frcp(a1*b1*gp);
    cst[r] = cp;
    float C2 = fexp2(cp * 2.8853900817779268f);
    h[r] = (C2 - 1.f) * frcp((1.f + O)*(C2 + 1.f));
  }
  p01 = cvtpk(h[0], h[1]);
  p23 = cvtpk(h[2], h[3]);
}

// One flag-synced diagonal iteration. S = d%3 (compile-time).
// Slots: read (S+2)%3, write S, x-write (S+1)%3.
template<int S>
__device__ __forceinline__ void diag_iter(char* lds, volatile int* wfl, volatile int* rfl,
    int d, int lw, int s, int lane,
    const bf16x8 (&wf)[4][4], const f32x4 (&bvv)[4], float (&cst)[4],
    float2 &xr, const float* __restrict__ xbase,
    int rdA, int wHbase, int xwAddr, int aInBase, int aRecBase){
  constexpr int RS = (S+2)%3;
  constexpr int XS = (S+1)%3;
  const bool active = (unsigned)(d - lw) <= 255u;

  // 1. wait for producers: wflag[lw-1..lw] >= d-1 (L0: own group only)
  if (lw > 0) poll8(wfl + (lw-1)*4, d-1);
  else        poll4(wfl, d-1);
  asm volatile("" ::: "memory");

  bf16x8 t0, t1, t2, t3;
  if (active){
    if (lw == 0){
      t0 = *reinterpret_cast<const bf16x8*>(lds + S*128 + rdA);            // x(d)
      t1 = *reinterpret_cast<const bf16x8*>(lds + aRecBase + RS*128 + rdA);
      t2 = *reinterpret_cast<const bf16x8*>(lds + aRecBase + RS*128 + (rdA^64));
    } else {
      t0 = *reinterpret_cast<const bf16x8*>(lds + aInBase  + RS*128 + rdA);
      t1 = *reinterpret_cast<const bf16x8*>(lds + aInBase  + RS*128 + (rdA^64));
      t2 = *reinterpret_cast<const bf16x8*>(lds + aRecBase + RS*128 + rdA);
      t3 = *reinterpret_cast<const bf16x8*>(lds + aRecBase + RS*128 + (rdA^64));
    }
  }
  // 2. reads retired -> release slots to producers
  asm volatile("s_waitcnt lgkmcnt(0)" ::: "memory");
  if (lane == 0) rfl[lw*4 + s] = d;

  // 3. compute
  unsigned xpk = 0, p01 = 0, p23 = 0;
  if (active){
    if (lw == 0){
      xpk = cvtpk(xr.x, xr.y);                       // x(d+1) -> LDS later
      int tn = d + 2; if (tn > 255) tn = 255;
      xr = *reinterpret_cast<const float2*>(xbase + (size_t)tn*32);
    }
    f32x4 A[4];
    __builtin_amdgcn_s_setprio(1);
    #pragma unroll
    for (int g = 0; g < 4; ++g){
      f32x4 c = bvv[g];
      c = __builtin_amdgcn_mfma_f32_16x16x32_bf16(wf[0][g], t0, c, 0, 0, 0);
      c = __builtin_amdgcn_mfma_f32_16x16x32_bf16(wf[1][g], t1, c, 0, 0, 0);
      A[g] = __builtin_amdgcn_mfma_f32_16x16x32_bf16(wf[2][g], t2, c, 0, 0, 0);
    }
    if (lw != 0){
      #pragma unroll
      for (int g = 0; g < 4; ++g)
        A[g] = __builtin_amdgcn_mfma_f32_16x16x32_bf16(wf[3][g], t3, A[g], 0, 0, 0);
    }
    __builtin_amdgcn_s_setprio(0);
    ew4(A, cst, p01, p23);
  }

  // 4. WAR guard: consumers of our region must be past d-2 (slot d-3 free)
  if (lw < 2) poll8(rfl + lw*4, d-2);
  else        poll4(rfl + 2*4, d-2);
  asm volatile("" ::: "memory");

  // 5. publish h(d) (and x(d+1)), then signal
  if (active){
    if (lw == 0)
      *reinterpret_cast<unsigned*>(lds + XS*128 + xwAddr) = xpk;
    *reinterpret_cast<uint2*>(lds + wHbase + S*128) = make_uint2(p01, p23);
  }
  asm volatile("s_waitcnt lgkmcnt(0)" ::: "memory");
  if (lane == 0) wfl[lw*4 + s] = d;
}

__global__ __launch_bounds__(768, 1) void lstm3_wave_kernel(
    const float* __restrict__ x,
    const float* Wih0, const float* Whh0, const float* bih0, const float* bhh0,
    const float* Wih1, const float* Whh1, const float* bih1, const float* bhh1,
    const float* Wih2, const float* Whh2, const float* bih2, const float* bhh2,
    const float* __restrict__ fc1w, const float* __restrict__ fc1b,
    const float* __restrict__ fc2w, const float* __restrict__ fc2b,
    float* __restrict__ out){
  __shared__ char lds[BT*RST];        // 24576 B
  __shared__ int wfl[12];
  __shared__ int rfl[12];
  __shared__ float fcbuf[BT*16];

  const int tid  = threadIdx.x;
  const int lane = tid & 63;
  const int wid  = tid >> 6;      // 0..11
  const int s    = wid & 3;       // 16-unit hidden slice
  const int lw   = wid >> 2;      // owned layer 0..2
  const int l15  = lane & 15;
  const int lhi  = lane >> 4;
  const int row0 = blockIdx.x * BT;

  const float* Wih = (lw == 0) ? Wih0 : ((lw == 1) ? Wih1 : Wih2);
  const float* Whh = (lw == 0) ? Whh0 : ((lw == 1) ? Whh1 : Whh2);
  const float* bih = (lw == 0) ? bih0 : ((lw == 1) ? bih1 : bih2);
  const float* bhh = (lw == 0) ? bhh0 : ((lw == 1) ? bhh1 : bhh2);
  const int IN = (lw == 0) ? 32 : 64;

  bf16x8 wf[4][4];
  f32x4 bvv[4];
  load_wb_rt(Wih, Whh, bih, bhh, IN, wf, bvv, s, l15, lhi);

  // Swizzled within-slot addresses (byte ^= (row&7)<<4, stays within 128 B).
  const int rdA = l15*RST + ((lhi*16) ^ ((l15 & 7) << 4));
  const int aInBase  = (lw == 1) ? 384 : 768;    // used only for lw>0
  const int aRecBase = 384 + lw*384;
  const int wHbase = l15*RST + (384 + lw*384) +
                     ((s*32 + lhi*8) ^ ((l15 & 7) << 4));
  const int xrow = (tid & 255) >> 4;
  const int xwAddr = xrow*RST + (((tid & 15)*4) ^ ((xrow & 7) << 4));
  const float* xbase = x + ((size_t)(row0 + xrow)*TSTEPS)*32 + (tid & 15)*2;

  // zero LDS (h(-1)=0 everywhere): 768 threads x 2 int4 = 24576 B
  *reinterpret_cast<int4*>(lds + tid*16) = make_int4(0, 0, 0, 0);
  *reinterpret_cast<int4*>(lds + 12288 + tid*16) = make_int4(0, 0, 0, 0);
  if (tid < 12){ wfl[tid] = -1; rfl[tid] = -1; }
  __syncthreads();
  float2 xr = make_float2(0.f, 0.f);
  if (tid < 256){                         // L0 waves stage x(0) into slot 0
    float2 v0 = *reinterpret_cast<const float2*>(xbase);
    *reinterpret_cast<unsigned*>(lds + xwAddr) = cvtpk(v0.x, v0.y);
    xr = *reinterpret_cast<const float2*>(xbase + 32);   // x(1)
  }
  __syncthreads();

  float cst[4] = {0.f, 0.f, 0.f, 0.f};

  // 258 = 86*3 diagonals, slot index compile-time via 3x unroll
  for (int k = 0; k < 86; ++k){
    int d = 3*k;
    diag_iter<0>(lds, wfl, rfl, d,   lw, s, lane, wf, bvv, cst, xr, xbase,
                 rdA, wHbase, xwAddr, aInBase, aRecBase);
    diag_iter<1>(lds, wfl, rfl, d+1, lw, s, lane, wf, bvv, cst, xr, xbase,
                 rdA, wHbase, xwAddr, aInBase, aRecBase);
    diag_iter<2>(lds, wfl, rfl, d+2, lw, s, lane, wf, bvv, cst, xr, xbase,
                 rdA, wHbase, xwAddr, aInBase, aRecBase);
  }

  __syncthreads();   // all h2(255) published (slot 257%3 = 2)

  // ---- fused FC head: h2(255) in H2 slot 2 -> byte 1152 + 256 ----
  if (tid < 256){
    const int row  = tid & 15;
    const int slot = tid >> 4;
    const int rx   = (row & 7) << 4;
    float hv[HID];
    #pragma unroll
    for (int i = 0; i < HID; ++i)
      hv[i] = bf2f(*reinterpret_cast<const ushort*>(
                   lds + row*RST + 1408 + ((i*2) ^ rx)));
    float p = 0.f;
    #pragma unroll
    for (int jj = 0; jj < 2; ++jj){
      int j = slot*2 + jj;
      float z = fc1b[j];
      #pragma unroll
      for (int i = 0; i < HID; ++i) z += hv[i]*fc1w[j*HID + i];
      z = fmaxf(z, 0.f);
      p += z * fc2w[j];
    }
    fcbuf[row*16 + slot] = p;
  }
  __syncthreads();
  if (tid < BT){
    float s2 = fc2b[0];
    #pragma unroll
    for (int k = 0; k < 16; ++k) s2 += fcbuf[tid*16 + k];
    out[row0 + tid] = s2;
  }
}

extern "C" void kernel_launch(void* const* d_in, const int* in_sizes, int n_in,
                              void* d_out, int out_size, void* d_ws, size_t ws_size,
                              hipStream_t stream){
  const float* x    = (const float*)d_in[0];
  const float* Wih0 = (const float*)d_in[1];
  const float* Whh0 = (const float*)d_in[2];
  const float* bih0 = (const float*)d_in[3];
  const float* bhh0 = (const float*)d_in[4];
  const float* Wih1 = (const float*)d_in[5];
  const float* Whh1 = (const float*)d_in[6];
  const float* bih1 = (const float*)d_in[7];
  const float* bhh1 = (const float*)d_in[8];
  const float* Wih2 = (const float*)d_in[9];
  const float* Whh2 = (const float*)d_in[10];
  const float* bih2 = (const float*)d_in[11];
  const float* bhh2 = (const float*)d_in[12];
  const float* fc1w = (const float*)d_in[13];
  const float* fc1b = (const float*)d_in[14];
  const float* fc2w = (const float*)d_in[15];
  const float* fc2b = (const float*)d_in[16];

  lstm3_wave_kernel<<<BATCH/BT, 768, 0, stream>>>(x,
      Wih0, Whh0, bih0, bhh0,
      Wih1, Whh1, bih1, bhh1,
      Wih2, Whh2, bih2, bhh2,
      fc1w, fc1b, fc2w, fc2b, (float*)d_out);
}

// Round 11
// 311.359 us; speedup vs baseline: 1.4683x; 1.4683x over previous
//
#include <hip/hip_runtime.h>

typedef __attribute__((ext_vector_type(8))) short bf16x8;
typedef __attribute__((ext_vector_type(4))) float f32x4;

#define HID 64
#define TSTEPS 256
#define BATCH 4096
#define BT 16
#define RST 1536          // bytes per LDS row
// per-row regions: X @0 (3 slots x 128B), H0 @384, H1 @768, H2 @1152 (3 x 128B each)

__device__ __forceinline__ float frcp(float x){ return __builtin_amdgcn_rcpf(x); }
__device__ __forceinline__ float fexp2(float x){ return __builtin_amdgcn_exp2f(x); }

__device__ __forceinline__ ushort f2bf(float f){
  unsigned u = __float_as_uint(f);
  u += 0x7fff + ((u>>16)&1);
  return (ushort)(u>>16);
}
__device__ __forceinline__ float bf2f(ushort u){ return __uint_as_float(((unsigned)u)<<16); }
__device__ __forceinline__ unsigned cvtpk(float lo, float hi){
  unsigned r;
  asm("v_cvt_pk_bf16_f32 %0, %1, %2" : "=v"(r) : "v"(lo), "v"(hi));
  return r;
}

__device__ __forceinline__ int min4(const int* p){
  int4 a = *reinterpret_cast<const int4*>(p);
  return min(min(a.x, a.y), min(a.z, a.w));
}

// Weights pre-scaled by log2(e) (gates i,f,o) / 2*log2(e) (gate g).
__device__ __forceinline__ void load_wb_rt(const float* __restrict__ Wih,
    const float* __restrict__ Whh, const float* __restrict__ bih,
    const float* __restrict__ bhh, int IN, bf16x8 (&wf)[4][4], f32x4 (&bvv)[4],
    int s, int l15, int lhi){
  const float L2E = 1.4426950408889634f;
  const int nk = (IN + 64) >> 5;          // 3 (layer0) or 4
  #pragma unroll
  for (int g = 0; g < 4; ++g){
    const float sc = (g == 2) ? 2.f*L2E : L2E;
    int n = g*64 + s*16 + l15;            // A-frag row (m = lane&15)
    #pragma unroll
    for (int r = 0; r < 4; ++r){
      int nr = g*64 + s*16 + lhi*4 + r;   // C/D row (m = lhi*4+r)
      bvv[g][r] = (bih[nr] + bhh[nr]) * sc;
    }
    #pragma unroll
    for (int kt = 0; kt < 4; ++kt){
      if (kt < nk){
        int kb = kt*32 + lhi*8;           // same kappa(lane,j) as act-frag reads
        const float* src = (kb < IN) ? (Wih + (size_t)n*IN + kb)
                                     : (Whh + (size_t)n*64 + (kb - IN));
        bf16x8 v;
        #pragma unroll
        for (int j = 0; j < 8; ++j) v[j] = (short)f2bf(src[j] * sc);
        wf[kt][g] = v;
      }
    }
  }
}

// Merged-denominator LSTM cell: 5 exp2 + 2 rcp per cell (pre-scaled gates).
__device__ __forceinline__ void ew4(const f32x4 (&A)[4], float (&cst)[4],
                                    unsigned &p01, unsigned &p23){
  float h[4];
  #pragma unroll
  for (int r = 0; r < 4; ++r){
    float Ai = fexp2(-A[0][r]);
    float Bf = fexp2(-A[1][r]);
    float G  = fexp2( A[2][r]);
    float O  = fexp2(-A[3][r]);
    float a1 = 1.f + Ai, b1 = 1.f + Bf, gp = G + 1.f, gm = G - 1.f;
    float cp = (cst[r]*a1*gp + b1*gm) * frcp(a1*b1*gp);
    cst[r] = cp;
    float C2 = fexp2(cp * 2.8853900817779268f);
    h[r] = (C2 - 1.f) * frcp((1.f + O)*(C2 + 1.f));
  }
  p01 = cvtpk(h[0], h[1]);
  p23 = cvtpk(h[2], h[3]);
}

// One flag-synced diagonal. S = d%3 (compile-time).
// Read slot (S+2)%3 (h(d-1)); write slot S (h(d)); x-write (S+1)%3 (x(d+1)).
// wfl[w]=d: wave w published h(d) (+x(d+1) if L0). rfl[w]=d: wave w's act
// reads for diag d have issued. MIN over each 4-wave group = true barrier
// semantics per group; per-wave DS-pipe in-order execution gives HW ordering
// (flag store lands at the banks after the preceding data reads/writes).
template<int S>
__device__ __forceinline__ void diag_iter(char* lds, volatile int* wfl, volatile int* rfl,
    int d, int lw, int widx, int lane,
    const bf16x8 (&wf)[4][4], const f32x4 (&bvv)[4], float (&cst)[4],
    float2 &xr, const float* __restrict__ xbase,
    int rdA, int wHbase, int xwAddr, int aInBase, int aRecBase){
  constexpr int RS = (S+2)%3;
  constexpr int XS = (S+1)%3;
  const bool active = (unsigned)(d - lw) <= 255u;

  // 1. producer poll: all waves of source groups published diag d-1
  if (lw > 0){
    const int* pa = (const int*)wfl + 4*(lw-1);
    for(;;){
      asm volatile("" ::: "memory");
      if (min(min4(pa), min4(pa+4)) >= d-1) break;
    }
  } else {
    const int* pa = (const int*)wfl;
    for(;;){
      asm volatile("" ::: "memory");
      if (min4(pa) >= d-1) break;
    }
  }
  asm volatile("" ::: "memory");

  // 2. act reads
  bf16x8 t0, t1, t2, t3;
  if (active){
    if (lw == 0){
      t0 = *reinterpret_cast<const bf16x8*>(lds + S*128 + rdA);            // x(d)
      t1 = *reinterpret_cast<const bf16x8*>(lds + aRecBase + RS*128 + rdA);
      t2 = *reinterpret_cast<const bf16x8*>(lds + aRecBase + RS*128 + (rdA^64));
    } else {
      t0 = *reinterpret_cast<const bf16x8*>(lds + aInBase  + RS*128 + rdA);
      t1 = *reinterpret_cast<const bf16x8*>(lds + aInBase  + RS*128 + (rdA^64));
      t2 = *reinterpret_cast<const bf16x8*>(lds + aRecBase + RS*128 + rdA);
      t3 = *reinterpret_cast<const bf16x8*>(lds + aRecBase + RS*128 + (rdA^64));
    }
  }
  asm volatile("" ::: "memory");
  // 3. read-done signal (DS pipe in-order: lands after the reads)
  if (lane == 0) rfl[widx] = d;

  // 4. compute
  unsigned xpk = 0, p01 = 0, p23 = 0;
  if (active){
    if (lw == 0){
      xpk = cvtpk(xr.x, xr.y);                       // x(d+1), written below
      int tn = d + 2; if (tn > 255) tn = 255;
      xr = *reinterpret_cast<const float2*>(xbase + (size_t)tn*32);
    }
    f32x4 A[4];
    __builtin_amdgcn_s_setprio(1);
    #pragma unroll
    for (int g = 0; g < 4; ++g){
      f32x4 c = bvv[g];
      c = __builtin_amdgcn_mfma_f32_16x16x32_bf16(wf[0][g], t0, c, 0, 0, 0);
      c = __builtin_amdgcn_mfma_f32_16x16x32_bf16(wf[1][g], t1, c, 0, 0, 0);
      A[g] = __builtin_amdgcn_mfma_f32_16x16x32_bf16(wf[2][g], t2, c, 0, 0, 0);
    }
    if (lw != 0){
      #pragma unroll
      for (int g = 0; g < 4; ++g)
        A[g] = __builtin_amdgcn_mfma_f32_16x16x32_bf16(wf[3][g], t3, A[g], 0, 0, 0);
    }
    __builtin_amdgcn_s_setprio(0);
    ew4(A, cst, p01, p23);
  }

  // 5. WAR poll: all reader waves issued their diag d-2 reads (slot free)
  if (lw < 2){
    const int* pa = (const int*)rfl + 4*lw;
    for(;;){
      asm volatile("" ::: "memory");
      if (min(min4(pa), min4(pa+4)) >= d-2) break;
    }
  } else {
    const int* pa = (const int*)rfl + 8;
    for(;;){
      asm volatile("" ::: "memory");
      if (min4(pa) >= d-2) break;
    }
  }
  asm volatile("" ::: "memory");

  // 6. publish h(d) (and x(d+1))
  if (active){
    if (lw == 0)
      *reinterpret_cast<unsigned*>(lds + XS*128 + xwAddr) = xpk;
    *reinterpret_cast<uint2*>(lds + wHbase + S*128) = make_uint2(p01, p23);
  }
  asm volatile("" ::: "memory");
  // 7. publish signal (DS pipe in-order: lands after the writes)
  if (lane == 0) wfl[widx] = d;
}

__global__ __launch_bounds__(768, 1) void lstm3_wave_kernel(
    const float* __restrict__ x,
    const float* Wih0, const float* Whh0, const float* bih0, const float* bhh0,
    const float* Wih1, const float* Whh1, const float* bih1, const float* bhh1,
    const float* Wih2, const float* Whh2, const float* bih2, const float* bhh2,
    const float* __restrict__ fc1w, const float* __restrict__ fc1b,
    const float* __restrict__ fc2w, const float* __restrict__ fc2b,
    float* __restrict__ out){
  __shared__ char lds[BT*RST];        // 24576 B
  __shared__ int wfl[12];
  __shared__ int rfl[12];
  __shared__ float fcbuf[BT*16];

  const int tid  = threadIdx.x;
  const int lane = tid & 63;
  const int wid  = tid >> 6;      // 0..11
  const int s    = wid & 3;       // 16-unit hidden slice
  const int lw   = wid >> 2;      // owned layer 0..2
  const int widx = lw*4 + s;      // flag index
  const int l15  = lane & 15;
  const int lhi  = lane >> 4;
  const int row0 = blockIdx.x * BT;

  const float* Wih = (lw == 0) ? Wih0 : ((lw == 1) ? Wih1 : Wih2);
  const float* Whh = (lw == 0) ? Whh0 : ((lw == 1) ? Whh1 : Whh2);
  const float* bih = (lw == 0) ? bih0 : ((lw == 1) ? bih1 : bih2);
  const float* bhh = (lw == 0) ? bhh0 : ((lw == 1) ? bhh1 : bhh2);
  const int IN = (lw == 0) ? 32 : 64;

  bf16x8 wf[4][4];
  f32x4 bvv[4];
  load_wb_rt(Wih, Whh, bih, bhh, IN, wf, bvv, s, l15, lhi);

  // Swizzled within-slot addresses (byte ^= (row&7)<<4, stays within 128 B).
  const int rdA = l15*RST + ((lhi*16) ^ ((l15 & 7) << 4));
  const int aInBase  = (lw == 1) ? 384 : 768;    // used only for lw>0
  const int aRecBase = 384 + lw*384;
  const int wHbase = l15*RST + (384 + lw*384) +
                     ((s*32 + lhi*8) ^ ((l15 & 7) << 4));
  const int xrow = (tid & 255) >> 4;
  const int xwAddr = xrow*RST + (((tid & 15)*4) ^ ((xrow & 7) << 4));
  const float* xbase = x + ((size_t)(row0 + xrow)*TSTEPS)*32 + (tid & 15)*2;

  // zero LDS (h(-1)=0 everywhere): 768 threads x 2 int4 = 24576 B
  *reinterpret_cast<int4*>(lds + tid*16) = make_int4(0, 0, 0, 0);
  *reinterpret_cast<int4*>(lds + 12288 + tid*16) = make_int4(0, 0, 0, 0);
  if (tid < 12){ wfl[tid] = -1; rfl[tid] = -1; }
  __syncthreads();
  float2 xr = make_float2(0.f, 0.f);
  if (tid < 256){                         // L0 waves stage x(0) into slot 0
    float2 v0 = *reinterpret_cast<const float2*>(xbase);
    *reinterpret_cast<unsigned*>(lds + xwAddr) = cvtpk(v0.x, v0.y);
    xr = *reinterpret_cast<const float2*>(xbase + 32);   // x(1)
  }
  __syncthreads();

  float cst[4] = {0.f, 0.f, 0.f, 0.f};

  // 258 = 86*3 diagonals, slot index compile-time via 3x unroll
  for (int k = 0; k < 86; ++k){
    int d = 3*k;
    diag_iter<0>(lds, wfl, rfl, d,   lw, widx, lane, wf, bvv, cst, xr, xbase,
                 rdA, wHbase, xwAddr, aInBase, aRecBase);
    diag_iter<1>(lds, wfl, rfl, d+1, lw, widx, lane, wf, bvv, cst, xr, xbase,
                 rdA, wHbase, xwAddr, aInBase, aRecBase);
    diag_iter<2>(lds, wfl, rfl, d+2, lw, widx, lane, wf, bvv, cst, xr, xbase,
                 rdA, wHbase, xwAddr, aInBase, aRecBase);
  }

  __syncthreads();   // all h2(255) published (slot 257%3 = 2)

  // ---- fused FC head: h2(255) in H2 slot 2 -> byte 1152 + 256 ----
  if (tid < 256){
    const int row  = tid & 15;
    const int slot = tid >> 4;
    const int rx   = (row & 7) << 4;
    float hv[HID];
    #pragma unroll
    for (int i = 0; i < HID; ++i)
      hv[i] = bf2f(*reinterpret_cast<const ushort*>(
                   lds + row*RST + 1408 + ((i*2) ^ rx)));
    float p = 0.f;
    #pragma unroll
    for (int jj = 0; jj < 2; ++jj){
      int j = slot*2 + jj;
      float z = fc1b[j];
      #pragma unroll
      for (int i = 0; i < HID; ++i) z += hv[i]*fc1w[j*HID + i];
      z = fmaxf(z, 0.f);
      p += z * fc2w[j];
    }
    fcbuf[row*16 + slot] = p;
  }
  __syncthreads();
  if (tid < BT){
    float s2 = fc2b[0];
    #pragma unroll
    for (int k = 0; k < 16; ++k) s2 += fcbuf[tid*16 + k];
    out[row0 + tid] = s2;
  }
}

extern "C" void kernel_launch(void* const* d_in, const int* in_sizes, int n_in,
                              void* d_out, int out_size, void* d_ws, size_t ws_size,
                              hipStream_t stream){
  const float* x    = (const float*)d_in[0];
  const float* Wih0 = (const float*)d_in[1];
  const float* Whh0 = (const float*)d_in[2];
  const float* bih0 = (const float*)d_in[3];
  const float* bhh0 = (const float*)d_in[4];
  const float* Wih1 = (const float*)d_in[5];
  const float* Whh1 = (const float*)d_in[6];
  const float* bih1 = (const float*)d_in[7];
  const float* bhh1 = (const float*)d_in[8];
  const float* Wih2 = (const float*)d_in[9];
  const float* Whh2 = (const float*)d_in[10];
  const float* bih2 = (const float*)d_in[11];
  const float* bhh2 = (const float*)d_in[12];
  const float* fc1w = (const float*)d_in[13];
  const float* fc1b = (const float*)d_in[14];
  const float* fc2w = (const float*)d_in[15];
  const float* fc2b = (const float*)d_in[16];

  lstm3_wave_kernel<<<BATCH/BT, 768, 0, stream>>>(x,
      Wih0, Whh0, bih0, bhh0,
      Wih1, Whh1, bih1, bhh1,
      Wih2, Whh2, bih2, bhh2,
      fc1w, fc1b, fc2w, fc2b, (float*)d_out);
}

// Round 13
// 249.552 us; speedup vs baseline: 1.8320x; 1.2477x over previous
//
#include <hip/hip_runtime.h>

typedef __attribute__((ext_vector_type(8))) short bf16x8;
typedef __attribute__((ext_vector_type(4))) float f32x4;
typedef __attribute__((ext_vector_type(2))) float f32x2;

#define HID 64
#define TSTEPS 256
#define BATCH 4096
#define BT 16
#define RST 1024          // bytes per LDS row
// byte-column regions within each 1024-B row (2 slots x 128 B each):
#define XOFF  0           // x: 32 bf16 cols used per slot
#define H0OFF 256
#define H1OFF 512
#define H2OFF 768

__device__ __forceinline__ float frcp(float x){ return __builtin_amdgcn_rcpf(x); }
__device__ __forceinline__ float fexp2(float x){ return __builtin_amdgcn_exp2f(x); }

// Barrier WITHOUT vmcnt drain: LDS ordering only.
__device__ __forceinline__ void lds_barrier(){
  asm volatile("s_waitcnt lgkmcnt(0)\n\ts_barrier" ::: "memory");
}

__device__ __forceinline__ ushort f2bf(float f){
  unsigned u = __float_as_uint(f);
  u += 0x7fff + ((u>>16)&1);
  return (ushort)(u>>16);
}
__device__ __forceinline__ float bf2f(ushort u){ return __uint_as_float(((unsigned)u)<<16); }
__device__ __forceinline__ unsigned cvtpk(float lo, float hi){
  unsigned r;
  asm("v_cvt_pk_bf16_f32 %0, %1, %2" : "=v"(r) : "v"(lo), "v"(hi));
  return r;
}

// Weight A-fragments pre-scaled by log2(e) (gates i,f,o) / 2*log2(e) (gate g).
// Bias per C/D row r: unit n = g*64 + s*16 + lhi*4 + r.
__device__ __forceinline__ void load_wb_rt(const float* __restrict__ Wih,
    const float* __restrict__ Whh, const float* __restrict__ bih,
    const float* __restrict__ bhh, int IN, bf16x8 (&wf)[4][4], f32x4 (&bvv)[4],
    int s, int l15, int lhi){
  const float L2E = 1.4426950408889634f;
  const int nk = (IN + 64) >> 5;          // 3 (layer0) or 4
  #pragma unroll
  for (int g = 0; g < 4; ++g){
    const float sc = (g == 2) ? 2.f*L2E : L2E;
    int n = g*64 + s*16 + l15;            // A-frag row (m = lane&15)
    #pragma unroll
    for (int r = 0; r < 4; ++r){
      int nr = g*64 + s*16 + lhi*4 + r;   // C/D row (m = lhi*4+r)
      bvv[g][r] = (bih[nr] + bhh[nr]) * sc;
    }
    #pragma unroll
    for (int kt = 0; kt < 4; ++kt){
      if (kt < nk){
        int kb = kt*32 + lhi*8;           // same kappa(lane,j) as act-frag reads
        const float* src = (kb < IN) ? (Wih + (size_t)n*IN + kb)
                                     : (Whh + (size_t)n*64 + (kb - IN));
        bf16x8 v;
        #pragma unroll
        for (int j = 0; j < 8; ++j) v[j] = (short)f2bf(src[j] * sc);
        wf[kt][g] = v;
      }
    }
  }
}

// Merged-denominator LSTM cell, cells paired as <2 x float> so the backend
// can emit v_pk_{add,mul,fma}_f32 (compiler-generated packed math — the
// hand-asm version mis-encoded; C vector ops are IEEE-identical to scalar).
__device__ __forceinline__ void ew4_pk(const f32x4 (&A)[4], f32x2 (&cst)[2],
                                       unsigned &p01, unsigned &p23){
  const f32x2 one  = { 1.f,  1.f };
  const f32x2 k2   = { 2.8853900817779268f, 2.8853900817779268f };
  unsigned pk[2];
  #pragma unroll
  for (int p = 0; p < 2; ++p){
    f32x2 Ai = { fexp2(-A[0][2*p]), fexp2(-A[0][2*p+1]) };   // e^{-i}
    f32x2 Bf = { fexp2(-A[1][2*p]), fexp2(-A[1][2*p+1]) };   // e^{-f}
    f32x2 G  = { fexp2( A[2][2*p]), fexp2( A[2][2*p+1]) };   // e^{2g}
    f32x2 O  = { fexp2(-A[3][2*p]), fexp2(-A[3][2*p+1]) };   // e^{-o}
    f32x2 a1 = Ai + one, b1 = Bf + one;
    f32x2 gp = G + one,  gm = G - one;
    f32x2 t   = a1 * gp;
    f32x2 num = cst[p]*t + b1*gm;
    f32x2 den = t * b1;
    f32x2 rr  = { frcp(den.x), frcp(den.y) };
    f32x2 cp  = num * rr;
    cst[p] = cp;
    f32x2 cps = cp * k2;
    f32x2 C2  = { fexp2(cps.x), fexp2(cps.y) };              // e^{2c'}
    f32x2 hn  = C2 - one;
    f32x2 dd  = (O + one) * (C2 + one);
    f32x2 r2  = { frcp(dd.x), frcp(dd.y) };
    f32x2 h   = hn * r2;
    pk[p] = cvtpk(h.x, h.y);
  }
  p01 = pk[0];
  p23 = pk[1];
}

// One diagonal: layer0@t=d, layer1@t=d-1, layer2@t=d-2. Wave (s,lw) owns
// layer lw, 16-unit slice s. Swapped MFMA (W as A, act as B): D[m=unit][n=batch]
// -> lane holds 4 consecutive units for batch l15 -> single b64 h-write.
template<int SL, bool L0, bool L1, bool L2>
__device__ __forceinline__ void diag_step(char* lds, int d, int lw,
    const bf16x8 (&wf)[4][4], const f32x4 (&bvv)[4], f32x2 (&cst)[2],
    float2 &xr, const float* __restrict__ xbase,
    int aIn, int aRec, int wH, int xwAddr){
  const int RSo = (SL^1)*128;
  const int SLo = SL*128;
  const bool act = (lw == 0) ? L0 : ((lw == 1) ? L1 : L2);

  if (act){
    // x staging first: consume xr (loaded a full diag ago), issue next load
    if (lw == 0){
      unsigned pk = cvtpk(xr.x, xr.y);
      *reinterpret_cast<unsigned*>(lds + xwAddr + RSo) = pk;   // x(d+1)
      int tn = d + 2; if (tn > TSTEPS-1) tn = TSTEPS-1;
      xr = *reinterpret_cast<const float2*>(xbase + (size_t)tn*32);
    }

    bf16x8 t0, t1, t2, t3;
    if (lw == 0){
      t0 = *reinterpret_cast<const bf16x8*>(lds + aIn + SLo);          // x(d)
      t1 = *reinterpret_cast<const bf16x8*>(lds + aRec + RSo);         // h0 kt0
      t2 = *reinterpret_cast<const bf16x8*>(lds + (aRec^64) + RSo);    // h0 kt1
    } else {
      t0 = *reinterpret_cast<const bf16x8*>(lds + aIn + RSo);          // h_{l-1} kt0
      t1 = *reinterpret_cast<const bf16x8*>(lds + (aIn^64) + RSo);     // h_{l-1} kt1
      t2 = *reinterpret_cast<const bf16x8*>(lds + aRec + RSo);         // h_l kt0
      t3 = *reinterpret_cast<const bf16x8*>(lds + (aRec^64) + RSo);    // h_l kt1
    }
    f32x4 A[4];
    __builtin_amdgcn_s_setprio(1);
    #pragma unroll
    for (int g = 0; g < 4; ++g){
      f32x4 c = bvv[g];
      c = __builtin_amdgcn_mfma_f32_16x16x32_bf16(wf[0][g], t0, c, 0, 0, 0);
      c = __builtin_amdgcn_mfma_f32_16x16x32_bf16(wf[1][g], t1, c, 0, 0, 0);
      A[g] = __builtin_amdgcn_mfma_f32_16x16x32_bf16(wf[2][g], t2, c, 0, 0, 0);
    }
    if (lw != 0){
      #pragma unroll
      for (int g = 0; g < 4; ++g)
        A[g] = __builtin_amdgcn_mfma_f32_16x16x32_bf16(wf[3][g], t3, A[g], 0, 0, 0);
    }
    __builtin_amdgcn_s_setprio(0);

    unsigned p01, p23;
    ew4_pk(A, cst, p01, p23);
    *reinterpret_cast<uint2*>(lds + wH + SLo) = make_uint2(p01, p23);  // b64
  }
  lds_barrier();
}

__global__ __launch_bounds__(768, 1) void lstm3_wave_kernel(
    const float* __restrict__ x,
    const float* Wih0, const float* Whh0, const float* bih0, const float* bhh0,
    const float* Wih1, const float* Whh1, const float* bih1, const float* bhh1,
    const float* Wih2, const float* Whh2, const float* bih2, const float* bhh2,
    const float* __restrict__ fc1w, const float* __restrict__ fc1b,
    const float* __restrict__ fc2w, const float* __restrict__ fc2b,
    float* __restrict__ out){
  __shared__ char lds[BT*RST];
  __shared__ float fcbuf[BT*16];

  const int tid  = threadIdx.x;
  const int lane = tid & 63;
  const int wid  = tid >> 6;      // 0..11
  const int s    = wid & 3;       // 16-unit hidden slice
  const int lw   = wid >> 2;      // owned layer 0..2
  const int l15  = lane & 15;
  const int lhi  = lane >> 4;
  const int row0 = blockIdx.x * BT;

  const float* Wih = (lw == 0) ? Wih0 : ((lw == 1) ? Wih1 : Wih2);
  const float* Whh = (lw == 0) ? Whh0 : ((lw == 1) ? Whh1 : Whh2);
  const float* bih = (lw == 0) ? bih0 : ((lw == 1) ? bih1 : bih2);
  const float* bhh = (lw == 0) ? bhh0 : ((lw == 1) ? bhh1 : bhh2);
  const int IN = (lw == 0) ? 32 : 64;

  bf16x8 wf[4][4];
  f32x4 bvv[4];
  load_wb_rt(Wih, Whh, bih, bhh, IN, wf, bvv, s, l15, lhi);

  // Swizzled LDS addresses (byte ^= (row&7)<<4 within 128-B region).
  const int rdA  = l15*RST + ((lhi*16) ^ ((l15 & 7) << 4));   // act frag reads
  const int aIn  = rdA + ((lw == 0) ? XOFF : ((lw == 1) ? H0OFF : H1OFF));
  const int aRec = rdA + (H0OFF + lw*256);
  // h-write: row = batch = l15, bytes (s*16+lhi*4)*2 .. +8 (one b64)
  const int wH = l15*RST + (H0OFF + lw*256) + ((s*32 + lhi*8) ^ ((l15 & 7) << 4));
  const int xrow = (tid & 255) >> 4;
  const int xwAddr = xrow*RST + XOFF + (((tid & 15)*4) ^ ((xrow & 7) << 4));
  const float* xbase = x + ((size_t)(row0 + xrow)*TSTEPS)*32 + (tid & 15)*2;

  // zero LDS (h(-1)=0 both slots): 768*16 + 256*16 = 16384 B
  *reinterpret_cast<int4*>(lds + tid*16) = make_int4(0, 0, 0, 0);
  if (tid < 256)
    *reinterpret_cast<int4*>(lds + 12288 + tid*16) = make_int4(0, 0, 0, 0);
  __syncthreads();
  float2 xr = make_float2(0.f, 0.f);
  if (tid < 256){                         // layer-0 waves stage x(0), hold x(1)
    float2 v0 = *reinterpret_cast<const float2*>(xbase);
    *reinterpret_cast<unsigned*>(lds + xwAddr) = cvtpk(v0.x, v0.y);  // slot 0
    xr = *reinterpret_cast<const float2*>(xbase + 32);
  }
  __syncthreads();

  f32x2 cst[2] = { {0.f, 0.f}, {0.f, 0.f} };

  #define ARGS lds, d, lw, wf, bvv, cst, xr, xbase, aIn, aRec, wH, xwAddr
  { int d = 0; diag_step<0, true, false, false>(ARGS); }
  { int d = 1; diag_step<1, true, true,  false>(ARGS); }
  for (int d = 2; d < 256; d += 2){
    diag_step<0, true, true, true>(ARGS);
    ++d;
    diag_step<1, true, true, true>(ARGS);
    --d;
  }
  { int d = 256; diag_step<0, false, true,  true>(ARGS); }
  { int d = 257; diag_step<1, false, false, true>(ARGS); }
  #undef ARGS

  __syncthreads();   // full drain before FC head

  // ---- fused FC head: final h2(255) is in H2 slot 1 (diag 257, SL=1) ----
  if (tid < 256){
    const int row  = tid & 15;
    const int slot = tid >> 4;
    const int rx   = (row & 7) << 4;
    float hv[HID];
    #pragma unroll
    for (int i = 0; i < HID; ++i)
      hv[i] = bf2f(*reinterpret_cast<const ushort*>(
                   lds + row*RST + (H2OFF + 128) + ((i*2) ^ rx)));
    float p = 0.f;
    #pragma unroll
    for (int jj = 0; jj < 2; ++jj){
      int j = slot*2 + jj;
      float z = fc1b[j];
      #pragma unroll
      for (int i = 0; i < HID; ++i) z += hv[i]*fc1w[j*HID + i];
      z = fmaxf(z, 0.f);
      p += z * fc2w[j];
    }
    fcbuf[row*16 + slot] = p;
  }
  __syncthreads();
  if (tid < BT){
    float s2 = fc2b[0];
    #pragma unroll
    for (int k = 0; k < 16; ++k) s2 += fcbuf[tid*16 + k];
    out[row0 + tid] = s2;
  }
}

extern "C" void kernel_launch(void* const* d_in, const int* in_sizes, int n_in,
                              void* d_out, int out_size, void* d_ws, size_t ws_size,
                              hipStream_t stream){
  const float* x    = (const float*)d_in[0];
  const float* Wih0 = (const float*)d_in[1];
  const float* Whh0 = (const float*)d_in[2];
  const float* bih0 = (const float*)d_in[3];
  const float* bhh0 = (const float*)d_in[4];
  const float* Wih1 = (const float*)d_in[5];
  const float* Whh1 = (const float*)d_in[6];
  const float* bih1 = (const float*)d_in[7];
  const float* bhh1 = (const float*)d_in[8];
  const float* Wih2 = (const float*)d_in[9];
  const float* Whh2 = (const float*)d_in[10];
  const float* bih2 = (const float*)d_in[11];
  const float* bhh2 = (const float*)d_in[12];
  const float* fc1w = (const float*)d_in[13];
  const float* fc1b = (const float*)d_in[14];
  const float* fc2w = (const float*)d_in[15];
  const float* fc2b = (const float*)d_in[16];

  lstm3_wave_kernel<<<BATCH/BT, 768, 0, stream>>>(x,
      Wih0, Whh0, bih0, bhh0,
      Wih1, Whh1, bih1, bhh1,
      Wih2, Whh2, bih2, bhh2,
      fc1w, fc1b, fc2w, fc2b, (float*)d_out);
}